// Round 4
// baseline (753.921 us; speedup 1.0000x reference)
//
#include <hip/hip_runtime.h>

#define D_IN 256
#define D_HALF 128

typedef __attribute__((ext_vector_type(8))) short short8;
typedef __attribute__((ext_vector_type(4))) float float4v;

__device__ __forceinline__ unsigned short f2bf(float f) {
    union { float f; unsigned u; } v; v.f = f;
    unsigned r = v.u + 0x7FFF + ((v.u >> 16) & 1);   // RNE
    return (unsigned short)(r >> 16);
}
__device__ __forceinline__ float bflo(unsigned u) { union { unsigned u; float f; } v; v.u = u << 16; return v.f; }
__device__ __forceinline__ float bfhi(unsigned u) { union { unsigned u; float f; } v; v.u = u & 0xffff0000u; return v.f; }

__device__ __forceinline__ void async16(const void* g, void* l) {
    __builtin_amdgcn_global_load_lds(
        (const __attribute__((address_space(1))) unsigned int*)g,
        (__attribute__((address_space(3))) unsigned int*)l, 16, 0, 0);
}

// ---------------- zero cnt ----------------

__global__ void zero_kernel(int* __restrict__ cnt, int M) {
    int i = blockIdx.x * blockDim.x + threadIdx.x;
    if (i < M) cnt[i] = 0;
}

// ---------------- fused: cast (role 0) + degree hist (role 1) ----------------

__global__ void cast_hist_kernel(const float* __restrict__ x, const float* __restrict__ Wf,
                                 const float* __restrict__ Wb, unsigned short* __restrict__ xb,
                                 unsigned short* __restrict__ wcat,
                                 const int* __restrict__ col, const int* __restrict__ row,
                                 int* __restrict__ cnt, int N, int E, int n4, int castBlocks) {
    const int w4 = (2 * D_HALF * D_IN) / 4;
    if (blockIdx.x < castBlocks) {
        int i = blockIdx.x * blockDim.x + threadIdx.x;
        if (i < n4) {
            float4 v = ((const float4*)x)[i];
            ushort4 o = { f2bf(v.x), f2bf(v.y), f2bf(v.z), f2bf(v.w) };
            ((ushort4*)xb)[i] = o;
        } else if (i < n4 + w4) {
            int j = i - n4;
            int elem = j * 4;
            const float* src = (elem < D_HALF * D_IN) ? (Wf + elem) : (Wb + (elem - D_HALF * D_IN));
            float4 v = *(const float4*)src;
            ushort4 o = { f2bf(v.x), f2bf(v.y), f2bf(v.z), f2bf(v.w) };
            ((ushort4*)wcat)[j] = o;
        }
    } else {
        int i = (blockIdx.x - castBlocks) * blockDim.x + threadIdx.x;
        if (i < E) {
            atomicAdd(&cnt[col[i]], 1);
            atomicAdd(&cnt[N + row[i]], 1);
        }
    }
}

// ---------------- fused: scan phase 1 (role 0) + inv_sqrt (role 1) ----------------

__global__ void scan1_inv_kernel(const int* __restrict__ cnt, int* __restrict__ offs,
                                 int* __restrict__ blksum,
                                 float* __restrict__ inv_in, float* __restrict__ inv_out,
                                 int M, int N, int nbScan) {
    __shared__ int s[256];
    if (blockIdx.x < nbScan) {
        int i = blockIdx.x * 256 + threadIdx.x;
        int v = (i < M) ? cnt[i] : 0;
        s[threadIdx.x] = v;
        __syncthreads();
        for (int d = 1; d < 256; d <<= 1) {
            int t = (threadIdx.x >= d) ? s[threadIdx.x - d] : 0;
            __syncthreads();
            s[threadIdx.x] += t;
            __syncthreads();
        }
        if (i < M) offs[i] = s[threadIdx.x] - v;
        if (threadIdx.x == 255) blksum[blockIdx.x] = s[255];
    } else {
        int i = (blockIdx.x - nbScan) * 256 + threadIdx.x;
        if (i < N) {
            inv_in[i]  = rsqrtf((float)(cnt[i] + 1));
            inv_out[i] = rsqrtf((float)(cnt[N + i] + 1));
        }
    }
}

__global__ void scan2_kernel(int* __restrict__ blksum, int nb) {
    __shared__ int s[1024];
    int v = (threadIdx.x < nb) ? blksum[threadIdx.x] : 0;
    s[threadIdx.x] = v;
    __syncthreads();
    for (int d = 1; d < 1024; d <<= 1) {
        int t = (threadIdx.x >= d) ? s[threadIdx.x - d] : 0;
        __syncthreads();
        s[threadIdx.x] += t;
        __syncthreads();
    }
    if (threadIdx.x < nb) blksum[threadIdx.x] = s[threadIdx.x] - v;
}

__global__ void scan3_kernel(int* __restrict__ offs, int* __restrict__ cursor,
                             const int* __restrict__ blksum, int M) {
    int i = blockIdx.x * 256 + threadIdx.x;
    if (i < M) {
        int v = offs[i] + blksum[blockIdx.x];
        offs[i] = v;
        cursor[i] = v;   // fill's atomic cursor starts at offs
    }
}

// ---------------- fused: bf16 MFMA GEMM (role 0) + CSR fill (role 1) ----------------
// gemm: 128x128 tile, BK=32, 256 threads (4 waves), 16x16x32 MFMA, XOR-swizzled LDS.
// fill: adj[atomicAdd(&cursor[key],1)] = other  (scatter-write bound, no VALU/MFMA)

#define BM 128
#define BN 128
#define BK 32

__global__ void fill_gemm_kernel(const unsigned short* __restrict__ xb,
                                 const unsigned short* __restrict__ wcat,
                                 unsigned short* __restrict__ zb,
                                 const int* __restrict__ col, const int* __restrict__ row,
                                 int* __restrict__ cursor, int* __restrict__ adj,
                                 int N, int E, int gemmBlocks) {
    __shared__ __align__(16) unsigned short As[BM * BK];
    __shared__ __align__(16) unsigned short Bs[BN * BK];
    const int tid = threadIdx.x;

    if (blockIdx.x < gemmBlocks) {
        const int wave = tid >> 6;
        const int lane = tid & 63;
        const int by = blockIdx.x & 1;        // N tile (2 tiles of 128)
        const int bx = blockIdx.x >> 1;       // M tile
        const int bm = bx * BM;
        const int bn = by * BN;
        const int warpM = wave >> 1;
        const int warpN = wave & 1;
        const int l15 = lane & 15;
        const int quad = lane >> 4;

        float4v acc[4][4];
        #pragma unroll
        for (int i = 0; i < 4; ++i)
            #pragma unroll
            for (int j = 0; j < 4; ++j)
                acc[i][j] = (float4v){0.f, 0.f, 0.f, 0.f};

        for (int kt = 0; kt < D_IN / BK; ++kt) {
            #pragma unroll
            for (int iss = 0; iss < 2; ++iss) {
                const int pbase = iss * 256 + wave * 64;
                const int p = pbase + lane;
                const int m = p >> 2;
                const int g = (p & 3) ^ ((m >> 1) & 3);
                int gm = bm + m; if (gm >= N) gm = N - 1;
                async16(xb + (size_t)gm * D_IN + kt * BK + g * 8, &As[pbase * 8]);
                async16(wcat + (size_t)(bn + m) * D_IN + kt * BK + g * 8, &Bs[pbase * 8]);
            }
            __syncthreads();

            short8 af[4], bfr[4];
            #pragma unroll
            for (int mi = 0; mi < 4; ++mi) {
                int m = warpM * 64 + mi * 16 + l15;
                af[mi] = *(const short8*)&As[m * BK + (quad ^ ((m >> 1) & 3)) * 8];
            }
            #pragma unroll
            for (int ni = 0; ni < 4; ++ni) {
                int n = warpN * 64 + ni * 16 + l15;
                bfr[ni] = *(const short8*)&Bs[n * BK + (quad ^ ((n >> 1) & 3)) * 8];
            }
            #pragma unroll
            for (int mi = 0; mi < 4; ++mi)
                #pragma unroll
                for (int ni = 0; ni < 4; ++ni)
                    acc[mi][ni] = __builtin_amdgcn_mfma_f32_16x16x32_bf16(af[mi], bfr[ni], acc[mi][ni], 0, 0, 0);
            __syncthreads();
        }

        #pragma unroll
        for (int mi = 0; mi < 4; ++mi) {
            #pragma unroll
            for (int reg = 0; reg < 4; ++reg) {
                int gm = bm + warpM * 64 + mi * 16 + quad * 4 + reg;
                if (gm < N) {
                    #pragma unroll
                    for (int ni = 0; ni < 4; ++ni) {
                        int gn = bn + warpN * 64 + ni * 16 + l15;
                        zb[(size_t)gm * D_IN + gn] = f2bf(acc[mi][ni][reg]);
                    }
                }
            }
        }
    } else {
        int i = (blockIdx.x - gemmBlocks) * 256 + tid;
        if (i < E) {
            int c = col[i], r = row[i];
            int pf = atomicAdd(&cursor[c], 1);
            adj[pf] = r;
            int pb = atomicAdd(&cursor[N + r], 1);
            adj[pb] = c;
        }
    }
}

// ---------------- gather: one wave per (node, dir), 4-deep ILP ----------------

__global__ void gather_kernel(const unsigned short* __restrict__ zb, const int* __restrict__ adj,
                              const int* __restrict__ offs, const int* __restrict__ cnt,
                              const float* __restrict__ inv_in, const float* __restrict__ inv_out,
                              const float* __restrict__ bias,
                              float* __restrict__ out, int N) {
    const int wave = threadIdx.x >> 6;
    const int lane = threadIdx.x & 63;
    const int slot = blockIdx.x * 4 + wave;
    if (slot >= 2 * N) return;
    const int node = slot >> 1;
    const int dir = slot & 1;
    const int csr = dir * N + node;
    const int beg = offs[csr];
    const int end = beg + cnt[csr];
    const float* __restrict__ wv = dir ? inv_in : inv_out;
    const int choff = dir * D_HALF + 2 * lane;   // two channels per lane

    float a0 = 0.f, a1 = 0.f, b0 = 0.f, b1 = 0.f;
    float c0 = 0.f, c1 = 0.f, d0 = 0.f, d1 = 0.f;
    int k = beg;
    for (; k + 3 < end; k += 4) {
        int n0 = adj[k], n1 = adj[k + 1], n2 = adj[k + 2], n3 = adj[k + 3];
        float w0 = wv[n0], w1 = wv[n1], w2 = wv[n2], w3 = wv[n3];
        unsigned u0 = *(const unsigned*)&zb[(size_t)n0 * D_IN + choff];
        unsigned u1 = *(const unsigned*)&zb[(size_t)n1 * D_IN + choff];
        unsigned u2 = *(const unsigned*)&zb[(size_t)n2 * D_IN + choff];
        unsigned u3 = *(const unsigned*)&zb[(size_t)n3 * D_IN + choff];
        a0 += w0 * bflo(u0); a1 += w0 * bfhi(u0);
        b0 += w1 * bflo(u1); b1 += w1 * bfhi(u1);
        c0 += w2 * bflo(u2); c1 += w2 * bfhi(u2);
        d0 += w3 * bflo(u3); d1 += w3 * bfhi(u3);
    }
    for (; k < end; ++k) {
        int n0 = adj[k];
        float w0 = wv[n0];
        unsigned u0 = *(const unsigned*)&zb[(size_t)n0 * D_IN + choff];
        a0 += w0 * bflo(u0); a1 += w0 * bfhi(u0);
    }
    float acc0 = (a0 + b0) + (c0 + d0);
    float acc1 = (a1 + b1) + (c1 + d1);

    const float scale = dir ? inv_out[node] : inv_in[node];
    const float invprod = inv_in[node] * inv_out[node];
    unsigned us = *(const unsigned*)&zb[(size_t)node * D_IN + choff];
    size_t oi = (size_t)node * D_IN + choff;
    float2 o;
    o.x = bias[choff]     + invprod * bflo(us) + scale * acc0;
    o.y = bias[choff + 1] + invprod * bfhi(us) + scale * acc1;
    *(float2*)&out[oi] = o;
}

// ---------------- launch ----------------

extern "C" void kernel_launch(void* const* d_in, const int* in_sizes, int n_in,
                              void* d_out, int out_size, void* d_ws, size_t ws_size,
                              hipStream_t stream) {
    const float* x    = (const float*)d_in[0];
    const int*   ei   = (const int*)d_in[1];
    const float* Wf   = (const float*)d_in[2];
    const float* Wb   = (const float*)d_in[3];
    const float* bias = (const float*)d_in[4];
    float* out = (float*)d_out;

    const int N = in_sizes[0] / D_IN;
    const int E = in_sizes[1] / 2;
    const int* col = ei;
    const int* rowp = ei + E;

    // workspace (~119 MB)
    char* ws = (char*)d_ws;
    unsigned short* xb = (unsigned short*)ws;   ws += (size_t)N * D_IN * sizeof(short);
    unsigned short* zb = (unsigned short*)ws;   ws += (size_t)N * D_IN * sizeof(short);
    unsigned short* wcat = (unsigned short*)ws; ws += (size_t)2 * D_HALF * D_IN * sizeof(short);
    int* cnt = (int*)ws;            ws += (size_t)2 * N * sizeof(int);
    int* cursor = (int*)ws;         ws += (size_t)2 * N * sizeof(int);
    int* offs = (int*)ws;           ws += (size_t)2 * N * sizeof(int);
    float* inv_in = (float*)ws;     ws += (size_t)N * sizeof(float);
    float* inv_out = (float*)ws;    ws += (size_t)N * sizeof(float);
    int* adj = (int*)ws;            ws += (size_t)2 * E * sizeof(int);
    int* blksum = (int*)ws;         ws += 1024 * sizeof(int);

    const int M = 2 * N;
    const int nb = (M + 255) / 256;               // scan blocks (<=1024)

    zero_kernel<<<(M + 255) / 256, 256, 0, stream>>>(cnt, M);

    const int n4 = N * D_IN / 4;
    const int w4 = (2 * D_HALF * D_IN) / 4;
    const int castBlocks = (n4 + w4 + 255) / 256;
    const int histBlocks = (E + 255) / 256;
    cast_hist_kernel<<<castBlocks + histBlocks, 256, 0, stream>>>(
        x, Wf, Wb, xb, wcat, col, rowp, cnt, N, E, n4, castBlocks);

    const int invBlocks = (N + 255) / 256;
    scan1_inv_kernel<<<nb + invBlocks, 256, 0, stream>>>(cnt, offs, blksum, inv_in, inv_out, M, N, nb);
    scan2_kernel<<<1, 1024, 0, stream>>>(blksum, nb);
    scan3_kernel<<<nb, 256, 0, stream>>>(offs, cursor, blksum, M);

    const int gemmBlocks = 2 * ((N + BM - 1) / BM);
    const int fillBlocks = (E + 255) / 256;
    fill_gemm_kernel<<<gemmBlocks + fillBlocks, 256, 0, stream>>>(
        xb, wcat, zb, col, rowp, cursor, adj, N, E, gemmBlocks);

    gather_kernel<<<(2 * N + 3) / 4, 256, 0, stream>>>(zb, adj, offs, cnt, inv_in, inv_out, bias, out, N);
}